// Round 9
// baseline (16168.944 us; speedup 1.0000x reference)
//
#include <hip/hip_runtime.h>
#include <stdint.h>

#define T_STEPS 4096
#define BATCH 32
#define HID 512
#define GROUPS 8            // blocks per batch
#define BLK_THREADS 1024    // 16 waves; 256 blocks = exactly 1/CU
#define NBLOCKS 256
#define BSLOT_DW 256                 // dwords per (slot,batch) h record: 8 groups x 32
#define SLOT_DW (BATCH * BSLOT_DW)   // dwords per rotation slot (8192 = 32 KB)
#define NSLOT 8                      // slot rotation depth (reuse distance 8)
#define TAG_STRIDE 16                // one 64B line of tags per batch

typedef _Float16 h2_t __attribute__((ext_vector_type(2)));
typedef uint32_t u32x8 __attribute__((ext_vector_type(8)));

__device__ inline uint32_t pack_h2(float a, float b) {
  h2_t v;
  v.x = (_Float16)a;
  v.y = (_Float16)b;
  return __builtin_bit_cast(uint32_t, v);
}

__device__ inline float fdot2(uint32_t a, uint32_t b, float c) {
  return __builtin_amdgcn_fdot2(__builtin_bit_cast(h2_t, a),
                                __builtin_bit_cast(h2_t, b), c, false);
}

__device__ inline uint64_t uni64(const void* p) {
  uint32_t lo = __builtin_amdgcn_readfirstlane((uint32_t)(uintptr_t)p);
  uint32_t hi = __builtin_amdgcn_readfirstlane((uint32_t)((uintptr_t)p >> 32));
  return ((uint64_t)hi << 32) | lo;
}

// R18 theory: R9==R11==R17 (~14.5-15.7ms regardless of inv COUNT) kills the
// inv-storm theory. The shared cost: BULK DATA through the scalar path —
// after any inv, 17 lines x 16 waves re-fill through the K$'s few MSHRs
// SERIALLY (~16-32 x 300cy = 5-10k cy/step == the measured 8500). Fix:
//   tags  -> scalar path, ONE line, single poller wave (cheap, proven).
//   data  -> VECTOR path (parallel MSHRs), freshness by ADDRESS ROTATION
//            (8 slots; an address is re-read only every 8 steps) plus ONE
//            buffer_inv per 4 steps by one wave (1/4000th of R14's toxic
//            per-iteration-all-waves rate) so no vL1 line can survive to
//            its slot's reuse. Every data fill is fresh-from-L2 with NO
//            per-access invalidation.
__device__ inline void kinv() {
  asm volatile("s_dcache_inv" ::: "memory");
}
__device__ inline void binv() {
  asm volatile("buffer_inv" ::: "memory");
}
__device__ inline u32x8 sload8(uint64_t p) {
  u32x8 v;
  asm volatile("s_load_dwordx8 %0, %1, 0x0\n\ts_waitcnt lgkmcnt(0)"
               : "=&s"(v) : "s"(p) : "memory");
  return v;
}
// Vector dword load, completion inside the asm (true data dep for consumers;
// placed after the volatile LDS spin so it cannot be hoisted above it).
__device__ inline uint32_t vload_dw(const uint32_t* p) {
  uint32_t v;
  asm volatile("global_load_dword %0, %1, off\n\ts_waitcnt vmcnt(0)"
               : "=v"(v) : "v"(p) : "memory");
  return v;
}

__device__ inline float sigf(float x) { return 1.0f / (1.0f + __expf(-x)); }
__device__ inline float tanh_fast(float x) {
  float a = fabsf(x);
  float e = __expf(-2.0f * a);
  float r = (1.0f - e) / (1.0f + e);
  return copysignf(r, x);
}

// Protocol per step t:
//   producer (wave 0): 32 packed-dword h-stores into slot (t+1)&7 ->
//                      s_waitcnt vmcnt(0) -> plain tag store (t+1).
//   poller  (wave 15): [every 4 steps: buffer_inv]  then
//                      { s_dcache_inv; s_load_dwordx8 tags; mirror to LDS }
//                      until all 8 >= t. ONE K$ line per CU in play.
//   consumers:         spin on LDS hflag[cs] >= t (per-group pipelining),
//                      then ONE vector dword load of their slice element
//                      from slot t&7 (parallel across lanes/waves), matvec
//                      via readlane -> fdot2 (R14's verified path).
// Freshness (data): slot address reused every 8 steps; wave-15's scrub every
// 4 steps (after the barrier chain) guarantees no vL1 copy survives from one
// use to the next; producer drained to L2 (vmcnt0) before the tag; same-XCD
// L2 via the claim protocol. Overwrite safety: reuse distance 8 > 2, same
// barrier-transitivity proof as the parity scheme since R9.
__global__ __launch_bounds__(BLK_THREADS)
void lstm_vecdata(const float* __restrict__ x0,
                  const float* __restrict__ W_ih,
                  const float* __restrict__ W_hh,
                  const float* __restrict__ b_ih,
                  const float* __restrict__ b_hh,
                  const float* __restrict__ W_lin,
                  const float* __restrict__ b_lin,
                  float* __restrict__ y,
                  uint32_t* __restrict__ h_ex,   // [NSLOT][BATCH][GROUPS][32]
                  uint32_t* __restrict__ tags,   // [BATCH][16] monotonic
                  int* __restrict__ claim)       // [8][16] per-XCD claim
{
  __shared__ float x0_lds[T_STEPS];     // 16 KB
  __shared__ float ylds[T_STEPS];       // 16 KB
  __shared__ float gacc[2][256];        // parity gate accumulators (intra-block)
  __shared__ int hflag[8];              // LDS mirror of the 8 group tags
  __shared__ int s_bg;

  const int tid = threadIdx.x;

  // ---- claim a (batch, group) slot on THIS block's physical XCD ----
  if (tid == 0) {
    uint32_t xcc;
    asm volatile("s_getreg_b32 %0, hwreg(HW_REG_XCC_ID)" : "=s"(xcc));
    xcc &= 7;
    int slot = atomicAdd(claim + xcc * 16, 1);   // one-time
    s_bg = (slot < 32) ? (int)(((4 * xcc + (slot >> 3)) << 3) | (slot & 7))
                       : -1;
  }
  __syncthreads();
  if (s_bg < 0) return;                  // surplus block
  const int b  = s_bg >> 3;              // batch (same XCD for all 8 groups)
  const int g  = s_bg & 7;               // group within batch
  const int u0 = g * 64;                 // first hidden unit owned
  const int wv = tid >> 6;               // wave 0..15
  const int rg = wv >> 3;                // row-group 0..1
  const int cs = wv & 7;                 // col-slice 0..7 == producer group
  const int l  = tid & 63;

  // ---- one-time: W_hh slice -> packed f16x2 -> VGPRs (R14 layout) ----
  uint32_t w0[32], w1[32];
  {
    const int r0 = 128 * rg + l;
    const int r1 = r0 + 64;
    const int R0 = (r0 >> 6) * HID + u0 + (r0 & 63);  // gate*512 + unit
    const int R1 = (r1 >> 6) * HID + u0 + (r1 & 63);
    const float2* p0 = (const float2*)(W_hh + (size_t)R0 * HID + 64 * cs);
    const float2* p1 = (const float2*)(W_hh + (size_t)R1 * HID + 64 * cs);
#pragma unroll
    for (int k = 0; k < 32; ++k) {
      float2 a = p0[k], c = p1[k];
      w0[k] = pack_h2(a.x, a.y);
      w1[k] = pack_h2(c.x, c.y);
    }
  }
  // ---- one-time: x0 column, y partials, gacc, flags ----
  for (int i = tid; i < T_STEPS; i += BLK_THREADS) {
    x0_lds[i] = x0[i * BATCH + b];
    ylds[i] = 0.f;
  }
  if (tid < 256) { gacc[0][tid] = 0.f; gacc[1][tid] = 0.f; }
  if (tid < 8) hflag[tid] = 0;          // tag 0 == "h_0 available"

  // ---- activation-lane constants (lanes 0..63 of wave 0) ----
  float c_state = 0.f;
  float wih_[4] = {0.f, 0.f, 0.f, 0.f}, bs_[4] = {0.f, 0.f, 0.f, 0.f};
  float wlin_u = 0.f, blin = 0.f;
  if (tid < 64) {
#pragma unroll
    for (int j = 0; j < 4; ++j) {
      int R = j * HID + u0 + tid;
      wih_[j] = W_ih[R];
      bs_[j] = b_ih[R] + b_hh[R];
    }
    wlin_u = W_lin[u0 + tid];
    blin = b_lin[0];
  }

  // ---- pointers ----
  uint32_t* tags_b = tags + b * TAG_STRIDE;
  const uint64_t tagu = uni64(tags_b);                 // poller address
  uint32_t* hb = h_ex + (size_t)b * BSLOT_DW;          // + slot*SLOT_DW
  uint32_t* fet_base = hb + 32 * cs + (l & 31);        // consumer elem addr
  uint32_t* pub_base = hb + 32 * g;                    // producer slice base

  __syncthreads();

  int dead = 0;
  for (int t = 0; t < T_STEPS; ++t) {
    const int sl = t & (NSLOT - 1);
    const int ns = (t + 1) & (NSLOT - 1);

    if (wv == 15) {
      // ---- vL1 scrub: one wave, every 4 steps (reuse distance is 8) ----
      if ((t & 3) == 0) binv();
      // ---- the ONE K$-polling wave: mirror tags into LDS ----
      if (!dead) {
        int guard = 0;
        for (;;) {
          kinv();
          u32x8 tg = sload8(tagu);
          if (l == 0) {
#pragma unroll
            for (int i = 0; i < 8; ++i)
              ((volatile int*)hflag)[i] = (int)tg[i];
          }
          bool ok = ((int)tg[0] >= t) & ((int)tg[1] >= t) &
                    ((int)tg[2] >= t) & ((int)tg[3] >= t) &
                    ((int)tg[4] >= t) & ((int)tg[5] >= t) &
                    ((int)tg[6] >= t) & ((int)tg[7] >= t);
          if (ok) break;
          if (++guard > (1 << 16)) { dead = 1; break; }  // anti-hang
          __builtin_amdgcn_s_sleep(1);
        }
        if (dead && l == 0) {            // release everyone, finish garbage
#pragma unroll
          for (int i = 0; i < 8; ++i)
            ((volatile int*)hflag)[i] = 0x7fffffff;
        }
      }
    } else {
      // ---- consumers: spin on own group's LDS flag ----
      int guard = 0;
      while (((volatile int*)hflag)[cs] < t) {
        if (++guard > (1 << 18)) break;  // anti-hang
        __builtin_amdgcn_s_sleep(1);
      }
    }

    // ---- data fetch: ONE vector dword per lane from slot sl (parallel
    //      MSHRs; address last touched 8 steps ago, scrubbed since) ----
    uint32_t hval = vload_dw(fet_base + sl * SLOT_DW);

    // ---- matvec: 2 rows x 64 cols per lane; h bcast via readlane (R14) ----
    float acc0a = 0.f, acc0b = 0.f, acc1a = 0.f, acc1b = 0.f;
#pragma unroll
    for (int k = 0; k < 32; k += 2) {
      uint32_t ha = __builtin_amdgcn_readlane(hval, k);
      uint32_t hb2 = __builtin_amdgcn_readlane(hval, k + 1);
      acc0a = fdot2(w0[k], ha, acc0a);
      acc1a = fdot2(w1[k], ha, acc1a);
      acc0b = fdot2(w0[k + 1], hb2, acc0b);
      acc1b = fdot2(w1[k + 1], hb2, acc1b);
    }
    atomicAdd(&gacc[t & 1][128 * rg + l], acc0a + acc0b);    // conflict-free
    atomicAdd(&gacc[t & 1][128 * rg + 64 + l], acc1a + acc1b);
    __syncthreads();   // the ONE block barrier per step

    // ---- activations + publish (wave 0, 64 lanes = 64 owned units) ----
    if (tid < 64) {
      const float xv = x0_lds[t];
      float gi = gacc[t & 1][tid]       + xv * wih_[0] + bs_[0];
      float gf = gacc[t & 1][tid + 64]  + xv * wih_[1] + bs_[1];
      float gg = gacc[t & 1][tid + 128] + xv * wih_[2] + bs_[2];
      float go = gacc[t & 1][tid + 192] + xv * wih_[3] + bs_[3];
      float si = sigf(gi), sf = sigf(gf), tg_ = tanh_fast(gg), so = sigf(go);
      c_state = sf * c_state + si * tg_;
      float h = so * tanh_fast(c_state);

      // publish into slot ns: even lanes store 32 packed dwords (one line)
      float hn = __shfl_down(h, 1, 64);
      if ((tid & 1) == 0) pub_base[ns * SLOT_DW + (tid >> 1)] = pack_h2(h, hn);
      // drain to L2, then the PLAIN tag store (R9-proven release)
      asm volatile("s_waitcnt vmcnt(0)" ::: "memory");
      if (tid == 0) tags_b[g] = (uint32_t)(t + 1);

      // recycle gacc[t&1] for step t+2 (ordering via the barrier chain)
      gacc[t & 1][tid] = 0.f;
      gacc[t & 1][tid + 64] = 0.f;
      gacc[t & 1][tid + 128] = 0.f;
      gacc[t & 1][tid + 192] = 0.f;

      // y partial (off critical path): fold 64 units -> ylds[t]
      float p = wlin_u * h;
#pragma unroll
      for (int m = 32; m >= 1; m >>= 1) p += __shfl_xor(p, m, 64);
      if (tid == 0) ylds[t] = p;
    }
  }

  // ---- drain: block partials -> global y (g==0 adds bias + residual) ----
  __syncthreads();
  for (int i = tid; i < T_STEPS; i += BLK_THREADS) {
    float val = ylds[i];
    if (g == 0) val += blin + x0_lds[i];
    unsafeAtomicAdd(&y[i * BATCH + b], val);
  }
}

extern "C" void kernel_launch(void* const* d_in, const int* in_sizes, int n_in,
                              void* d_out, int out_size, void* d_ws, size_t ws_size,
                              hipStream_t stream) {
  const float* x0    = (const float*)d_in[0];
  const float* W_ih  = (const float*)d_in[1];
  const float* W_hh  = (const float*)d_in[2];
  const float* b_ih  = (const float*)d_in[3];
  const float* b_hh  = (const float*)d_in[4];
  const float* W_lin = (const float*)d_in[5];
  const float* b_lin = (const float*)d_in[6];
  float* y = (float*)d_out;

  uint32_t* h_ex = (uint32_t*)d_ws;                    // 8 x 32 KB slots
  uint32_t* tags = h_ex + NSLOT * SLOT_DW;             // 2 KB (64B/batch)
  int* claim     = (int*)(tags + BATCH * TAG_STRIDE);  // 512 B
  const size_t init_bytes =
      (size_t)(NSLOT * SLOT_DW + BATCH * TAG_STRIDE) * sizeof(uint32_t)
      + 8 * 16 * sizeof(int);

  // memset 0: slot-0 h = 0 (== h0), tags = 0 ("h_0 available"), claim = 0
  (void)hipMemsetAsync(d_ws, 0, init_bytes, stream);
  (void)hipMemsetAsync(d_out, 0, (size_t)out_size * sizeof(float), stream);

  hipLaunchKernelGGL(lstm_vecdata, dim3(NBLOCKS), dim3(BLK_THREADS), 0, stream,
                     x0, W_ih, W_hh, b_ih, b_hh, W_lin, b_lin, y, h_ex, tags,
                     claim);
}

// Round 10
// 13979.388 us; speedup vs baseline: 1.1566x; 1.1566x over previous
//
#include <hip/hip_runtime.h>
#include <stdint.h>

#define T_STEPS 4096
#define BATCH 32
#define HID 512
#define GROUPS 8            // blocks per batch
#define BLK_THREADS 1024    // 16 waves; 256 blocks = exactly 1/CU
#define NBLOCKS 256
#define SLOT_DW (BATCH * GROUPS * 64)  // dwords per parity slot (16384 = 64 KB)

typedef _Float16 h2_t __attribute__((ext_vector_type(2)));
typedef uint32_t u32x8 __attribute__((ext_vector_type(8)));

__device__ inline uint32_t pack_h2(float a, float b) {
  h2_t v;
  v.x = (_Float16)a;
  v.y = (_Float16)b;
  return __builtin_bit_cast(uint32_t, v);
}

__device__ inline float fdot2(uint32_t a, uint32_t b, float c) {
  return __builtin_amdgcn_fdot2(__builtin_bit_cast(h2_t, a),
                                __builtin_bit_cast(h2_t, b), c, false);
}

__device__ inline uint64_t uni64(const void* p) {
  uint32_t lo = __builtin_amdgcn_readfirstlane((uint32_t)(uintptr_t)p);
  uint32_t hi = __builtin_amdgcn_readfirstlane((uint32_t)((uintptr_t)p >> 32));
  return ((uint64_t)hi << 32) | lo;
}

__device__ inline void kinv() {
  asm volatile("s_dcache_inv" ::: "memory");
}

// R11's fused poll+fetch (best measured: 14.49 ms): 8 scalar loads issued
// back-to-back, ONE lgkmcnt(0) — the 36 useful dwords (32 data + 4 tags).
__device__ inline void sload_rec(uint64_t p, u32x8* d0, u32x8* d1,
                                 u32x8* d2, u32x8* d3,
                                 uint32_t* t0, uint32_t* t1,
                                 uint32_t* t2, uint32_t* t3) {
  asm volatile("s_load_dwordx8 %0, %8, 0x0\n\t"
               "s_load_dword %4, %8, 0x20\n\t"
               "s_load_dwordx8 %1, %8, 0x40\n\t"
               "s_load_dword %5, %8, 0x60\n\t"
               "s_load_dwordx8 %2, %8, 0x80\n\t"
               "s_load_dword %6, %8, 0xa0\n\t"
               "s_load_dwordx8 %3, %8, 0xc0\n\t"
               "s_load_dword %7, %8, 0xe0\n\t"
               "s_waitcnt lgkmcnt(0)"
               : "=&s"(*d0), "=&s"(*d1), "=&s"(*d2), "=&s"(*d3),
                 "=&s"(*t0), "=&s"(*t1), "=&s"(*t2), "=&s"(*t3)
               : "s"(p) : "memory");
}

__device__ inline float sigf(float x) { return 1.0f / (1.0f + __expf(-x)); }
__device__ inline float tanh_fast(float x) {
  float a = fabsf(x);
  float e = __expf(-2.0f * a);
  float r = (1.0f - e) / (1.0f + e);
  return copysignf(r, x);
}

// Round 19: contention/serialization attack. Transport = R11's tagged-line
// scalar protocol, byte-identical (every clean transport measured 14.5-16.7
// ms -> the bottleneck is transport-INdependent). Changes:
//  1. NO in-loop __syncthreads. Waves 1-15: matvec -> gacc atomicAdds ->
//     LDS arrive[sl]++ -> immediately poll step t+1 (detect overlaps wave
//     0's activation+publish tail). Wave 0 alone spins on arrive[sl]==16.
//     Safety: gacc/arrive parity-buffered; remote blocks reach their t+2
//     contribution only after our t+1 publish (tag dependency), which
//     follows our zero/reset — same transitivity proof as the barrier.
//  2. s_setprio(1) around the critical dataflow (matvec+reduce; wave 0's
//     activation through publish), prio 0 while spinning — spin loops of
//     up-to-15 waves share 4 SIMD issue ports with the critical wave.
//  3. s_sleep(2) (128 cy) poll quantum — halves spin issue duty.
__global__ __launch_bounds__(BLK_THREADS)
void lstm_nobar(const float* __restrict__ x0,
                const float* __restrict__ W_ih,
                const float* __restrict__ W_hh,
                const float* __restrict__ b_ih,
                const float* __restrict__ b_hh,
                const float* __restrict__ W_lin,
                const float* __restrict__ b_lin,
                float* __restrict__ y,
                uint32_t* __restrict__ h_ex,   // [2][BATCH][GROUPS][64]
                int* __restrict__ claim)       // [8][16] per-XCD claim ctrs
{
  __shared__ float x0_lds[T_STEPS];     // 16 KB
  __shared__ float ylds[T_STEPS];       // 16 KB
  __shared__ float gacc[2][256];        // parity-buffered gate accumulators
  __shared__ int arrive[2];             // parity arrival counters
  __shared__ int s_bg;

  const int tid = threadIdx.x;

  // ---- claim a (batch, group) slot on THIS block's physical XCD ----
  if (tid == 0) {
    uint32_t xcc;
    asm volatile("s_getreg_b32 %0, hwreg(HW_REG_XCC_ID)" : "=s"(xcc));
    xcc &= 7;
    int slot = atomicAdd(claim + xcc * 16, 1);   // one-time
    s_bg = (slot < 32) ? (int)(((4 * xcc + (slot >> 3)) << 3) | (slot & 7))
                       : -1;
  }
  __syncthreads();
  if (s_bg < 0) return;                  // surplus block
  const int b  = s_bg >> 3;              // batch (same XCD for all 8 groups)
  const int g  = s_bg & 7;               // group within batch
  const int u0 = g * 64;                 // first hidden unit owned
  const int wv = tid >> 6;               // wave 0..15
  const int rg = wv >> 3;                // row-group 0..1
  const int cs = wv & 7;                 // col-slice 0..7 == producer group
  const int l  = tid & 63;

  // ---- one-time: W_hh slice -> packed f16x2 -> VGPRs ----
  uint32_t w0[32], w1[32];
  {
    const int r0 = 128 * rg + l;
    const int r1 = r0 + 64;
    const int R0 = (r0 >> 6) * HID + u0 + (r0 & 63);  // gate*512 + unit
    const int R1 = (r1 >> 6) * HID + u0 + (r1 & 63);
    const float2* p0 = (const float2*)(W_hh + (size_t)R0 * HID + 64 * cs);
    const float2* p1 = (const float2*)(W_hh + (size_t)R1 * HID + 64 * cs);
#pragma unroll
    for (int k = 0; k < 32; ++k) {
      float2 a = p0[k], c = p1[k];
      w0[k] = pack_h2(a.x, a.y);
      w1[k] = pack_h2(c.x, c.y);
    }
  }
  // ---- one-time: x0 column, y partials, gacc, arrive ----
  for (int i = tid; i < T_STEPS; i += BLK_THREADS) {
    x0_lds[i] = x0[i * BATCH + b];
    ylds[i] = 0.f;
  }
  if (tid < 256) { gacc[0][tid] = 0.f; gacc[1][tid] = 0.f; }
  if (tid < 2) arrive[tid] = 0;

  // ---- activation-lane constants (lanes 0..63 of wave 0) ----
  float c_state = 0.f;
  float wih_[4] = {0.f, 0.f, 0.f, 0.f}, bs_[4] = {0.f, 0.f, 0.f, 0.f};
  float wlin_u = 0.f, blin = 0.f;
  if (tid < 64) {
#pragma unroll
    for (int j = 0; j < 4; ++j) {
      int R = j * HID + u0 + tid;
      wih_[j] = W_ih[R];
      bs_[j] = b_ih[R] + b_hh[R];
    }
    wlin_u = W_lin[u0 + tid];
    blin = b_lin[0];
  }

  // ---- wave-uniform SGPR addresses (R11 layout: 4 tagged lines/record) ----
  uint32_t* hb = h_ex + (size_t)b * (GROUPS * 64);
  const uint64_t dpu[2] = { uni64(hb + 64 * cs),
                            uni64(hb + SLOT_DW + 64 * cs) };
  uint32_t* pub01[2] = { hb + 64 * g, hb + SLOT_DW + 64 * g };

  __syncthreads();

  int dead = 0;
  for (int t = 0; t < T_STEPS; ++t) {
    const int sl = t & 1, ns = sl ^ 1;

    // ---- fused poll+fetch (R11): inv; load 4 tagged lines; check tags ----
    u32x8 D0, D1, D2, D3;
    uint32_t tg0, tg1, tg2, tg3;
    {
      const uint32_t want = (uint32_t)t;
      int guard = 0;
      for (;;) {
        kinv();
        sload_rec(dpu[sl], &D0, &D1, &D2, &D3, &tg0, &tg1, &tg2, &tg3);
        if ((tg0 == want) & (tg1 == want) &
            (tg2 == want) & (tg3 == want)) break;
        if (dead || ++guard > (1 << 17)) { dead = 1; break; }  // anti-hang
        __builtin_amdgcn_s_sleep(2);     // 128-cy quantum: low spin duty
      }
    }

    // ---- critical dataflow: boost priority ----
    __builtin_amdgcn_s_setprio(1);
    float acc0a = 0.f, acc0b = 0.f, acc1a = 0.f, acc1b = 0.f;
#pragma unroll
    for (int k = 0; k < 8; ++k) {
      acc0a = fdot2(w0[k],      D0[k], acc0a);
      acc1a = fdot2(w1[k],      D0[k], acc1a);
      acc0b = fdot2(w0[8 + k],  D1[k], acc0b);
      acc1b = fdot2(w1[8 + k],  D1[k], acc1b);
      acc0a = fdot2(w0[16 + k], D2[k], acc0a);
      acc1a = fdot2(w1[16 + k], D2[k], acc1a);
      acc0b = fdot2(w0[24 + k], D3[k], acc0b);
      acc1b = fdot2(w1[24 + k], D3[k], acc1b);
    }
    atomicAdd(&gacc[sl][128 * rg + l], acc0a + acc0b);      // conflict-free
    atomicAdd(&gacc[sl][128 * rg + 64 + l], acc1a + acc1b);
    asm volatile("" ::: "memory");       // keep DS order: adds before inc
    if (l == 0) atomicAdd(&arrive[sl], 1);
    __builtin_amdgcn_s_setprio(0);
    // waves 1-15 fall through to poll t+1 NOW (overlaps wave 0's tail)

    // ---- activation + publish (wave 0 only; no block barrier) ----
    if (tid < 64) {
      // wait for all 16 waves' contributions (self included)
      {
        int guard = 0;
        while (((volatile int*)arrive)[sl] < 16) {
          if (++guard > (1 << 20)) break;          // anti-hang
        }
      }
      asm volatile("" ::: "memory");     // no hoisting gacc reads above spin
      __builtin_amdgcn_s_setprio(1);
      arrive[sl] = 0;                    // reset for t+2 (gated by tag chain)

      const float xv = x0_lds[t];
      float gi = gacc[sl][tid]       + xv * wih_[0] + bs_[0];
      float gf = gacc[sl][tid + 64]  + xv * wih_[1] + bs_[1];
      float gg = gacc[sl][tid + 128] + xv * wih_[2] + bs_[2];
      float go = gacc[sl][tid + 192] + xv * wih_[3] + bs_[3];
      float si = sigf(gi), sf = sigf(gf), tg_ = tanh_fast(gg), so = sigf(go);
      c_state = sf * c_state + si * tg_;
      float h = so * tanh_fast(c_state);

      // publish: 36-lane predicated store of 4 self-certifying lines
      // (tag in-line with data: no drain, no separate counter — R11-proven).
      float hn = __shfl_down(h, 1, 64);
      uint32_t val = 0;
      int doff = 0;
      bool act = false;
      if ((tid & 1) == 0) {
        int j = tid >> 1;
        val = pack_h2(h, hn);
        doff = ((j >> 3) << 4) + (j & 7);
        act = true;
      } else if (tid < 8) {
        int L = (tid - 1) >> 1;
        val = (uint32_t)(t + 1);
        doff = (L << 4) + 8;
        act = true;
      }
      if (act) pub01[ns][doff] = val;

      // recycle gacc[sl] for t+2 (ds in-order per wave; tag chain gates reuse)
      gacc[sl][tid] = 0.f;
      gacc[sl][tid + 64] = 0.f;
      gacc[sl][tid + 128] = 0.f;
      gacc[sl][tid + 192] = 0.f;

      // y partial (off critical path)
      float p = wlin_u * h;
#pragma unroll
      for (int m = 32; m >= 1; m >>= 1) p += __shfl_xor(p, m, 64);
      if (tid == 0) ylds[t] = p;
      __builtin_amdgcn_s_setprio(0);
    }
  }

  // ---- drain: block partials -> global y (g==0 adds bias + residual) ----
  __syncthreads();
  for (int i = tid; i < T_STEPS; i += BLK_THREADS) {
    float val = ylds[i];
    if (g == 0) val += blin + x0_lds[i];
    unsafeAtomicAdd(&y[i * BATCH + b], val);
  }
}

extern "C" void kernel_launch(void* const* d_in, const int* in_sizes, int n_in,
                              void* d_out, int out_size, void* d_ws, size_t ws_size,
                              hipStream_t stream) {
  const float* x0    = (const float*)d_in[0];
  const float* W_ih  = (const float*)d_in[1];
  const float* W_hh  = (const float*)d_in[2];
  const float* b_ih  = (const float*)d_in[3];
  const float* b_hh  = (const float*)d_in[4];
  const float* W_lin = (const float*)d_in[5];
  const float* b_lin = (const float*)d_in[6];
  float* y = (float*)d_out;

  uint32_t* h_ex = (uint32_t*)d_ws;                    // 2 x 64 KB slots
  int* claim     = (int*)(h_ex + 2 * SLOT_DW);         // 512 B
  const size_t init_bytes = (size_t)2 * SLOT_DW * sizeof(uint32_t)
                            + 8 * 16 * sizeof(int);

  // memset 0: slot-0 tags = 0 with h = 0 (== "h_0 available"), claim = 0
  (void)hipMemsetAsync(d_ws, 0, init_bytes, stream);
  (void)hipMemsetAsync(d_out, 0, (size_t)out_size * sizeof(float), stream);

  hipLaunchKernelGGL(lstm_nobar, dim3(NBLOCKS), dim3(BLK_THREADS), 0, stream,
                     x0, W_ih, W_hh, b_ih, b_hh, W_lin, b_lin, y, h_ex, claim);
}

// Round 11
// 13971.049 us; speedup vs baseline: 1.1573x; 1.0006x over previous
//
#include <hip/hip_runtime.h>
#include <stdint.h>

#define T_STEPS 4096
#define BATCH 32
#define HID 512
#define GROUPS 8            // blocks per batch
#define BLK_THREADS 512     // 8 waves: halves fan-in jitter, doubles ILP/wave
#define NBLOCKS 256
#define SLOT_DW (BATCH * GROUPS * 64)  // dwords per parity slot (16384 = 64 KB)

typedef _Float16 h2_t __attribute__((ext_vector_type(2)));
typedef uint32_t u32x8 __attribute__((ext_vector_type(8)));

__device__ inline uint32_t pack_h2(float a, float b) {
  h2_t v;
  v.x = (_Float16)a;
  v.y = (_Float16)b;
  return __builtin_bit_cast(uint32_t, v);
}

__device__ inline float fdot2(uint32_t a, uint32_t b, float c) {
  return __builtin_amdgcn_fdot2(__builtin_bit_cast(h2_t, a),
                                __builtin_bit_cast(h2_t, b), c, false);
}

__device__ inline uint64_t uni64(const void* p) {
  uint32_t lo = __builtin_amdgcn_readfirstlane((uint32_t)(uintptr_t)p);
  uint32_t hi = __builtin_amdgcn_readfirstlane((uint32_t)((uintptr_t)p >> 32));
  return ((uint64_t)hi << 32) | lo;
}

__device__ inline void kinv() {
  asm volatile("s_dcache_inv" ::: "memory");
}

// R11's fused poll+fetch (transport of every best round): 8 scalar loads
// back-to-back, ONE lgkmcnt(0) — 36 useful dwords (32 data + 4 in-line tags).
__device__ inline void sload_rec(uint64_t p, u32x8* d0, u32x8* d1,
                                 u32x8* d2, u32x8* d3,
                                 uint32_t* t0, uint32_t* t1,
                                 uint32_t* t2, uint32_t* t3) {
  asm volatile("s_load_dwordx8 %0, %8, 0x0\n\t"
               "s_load_dword %4, %8, 0x20\n\t"
               "s_load_dwordx8 %1, %8, 0x40\n\t"
               "s_load_dword %5, %8, 0x60\n\t"
               "s_load_dwordx8 %2, %8, 0x80\n\t"
               "s_load_dword %6, %8, 0xa0\n\t"
               "s_load_dwordx8 %3, %8, 0xc0\n\t"
               "s_load_dword %7, %8, 0xe0\n\t"
               "s_waitcnt lgkmcnt(0)"
               : "=&s"(*d0), "=&s"(*d1), "=&s"(*d2), "=&s"(*d3),
                 "=&s"(*t0), "=&s"(*t1), "=&s"(*t2), "=&s"(*t3)
               : "s"(p) : "memory");
}

__device__ inline float sigf(float x) { return 1.0f / (1.0f + __expf(-x)); }
__device__ inline float tanh_fast(float x) {
  float a = fabsf(x);
  float e = __expf(-2.0f * a);
  float r = (1.0f - e) / (1.0f + e);
  return copysignf(r, x);
}

// Round 20: fan-in/quantum attack. Transport byte-identical to R11/R19.
// Post-mortem arithmetic: ~8200 cy/step, ~800-1400 useful VALU issue,
// ~6800 cy WAIT — transport-independent across 10 rounds. Residual causes:
// max-of-16 fan-in jitter, s_sleep detect quantum (64-128 cy/hop on the
// critical chain), DVFS clock-down on sleep-idle SIMDs.
//  1. 8 waves (512 thr): each wave owns ALL 4 gate rows of its col-slice
//     (128 fdot2/lane, 8 chains, 128 weight VGPRs). Arrivals 16->8; spin
//     population halved; per-wave ILP doubled.
//  2. HOT SPIN everywhere (no s_sleep): detect at iteration granularity,
//     SIMDs stay busy -> no DVFS idle-down. Issue contention handled by
//     setprio (spin at prio 0, dataflow at prio 1).
//  3. No block barrier (R19): waves arrive-count and immediately poll t+1;
//     wave 0 alone gathers, activates, publishes tagged lines.
// Safety proofs (parity slots, tag monotonicity, gacc recycle) unchanged.
__global__ __launch_bounds__(BLK_THREADS)
void lstm_w8(const float* __restrict__ x0,
             const float* __restrict__ W_ih,
             const float* __restrict__ W_hh,
             const float* __restrict__ b_ih,
             const float* __restrict__ b_hh,
             const float* __restrict__ W_lin,
             const float* __restrict__ b_lin,
             float* __restrict__ y,
             uint32_t* __restrict__ h_ex,   // [2][BATCH][GROUPS][64]
             int* __restrict__ claim)       // [8][16] per-XCD claim ctrs
{
  __shared__ float x0_lds[T_STEPS];     // 16 KB
  __shared__ float ylds[T_STEPS];       // 16 KB
  __shared__ float gacc[2][256];        // parity-buffered gate accumulators
  __shared__ int arrive[2];             // parity arrival counters
  __shared__ int s_bg;

  const int tid = threadIdx.x;

  // ---- claim a (batch, group) slot on THIS block's physical XCD ----
  if (tid == 0) {
    uint32_t xcc;
    asm volatile("s_getreg_b32 %0, hwreg(HW_REG_XCC_ID)" : "=s"(xcc));
    xcc &= 7;
    int slot = atomicAdd(claim + xcc * 16, 1);   // one-time
    s_bg = (slot < 32) ? (int)(((4 * xcc + (slot >> 3)) << 3) | (slot & 7))
                       : -1;
  }
  __syncthreads();
  if (s_bg < 0) return;                  // surplus block
  const int b  = s_bg >> 3;              // batch (same XCD for all 8 groups)
  const int g  = s_bg & 7;               // group within batch
  const int u0 = g * 64;                 // first hidden unit owned
  const int wv = tid >> 6;               // wave 0..7
  const int cs = wv;                     // col-slice == producer group
  const int l  = tid & 63;

  // ---- one-time: W_hh slice -> packed f16x2 -> VGPRs ----
  // Wave cs owns acc rows j = 64a + l (a = gate 0..3), cols 64cs..64cs+63.
  uint32_t w[4][32];
#pragma unroll
  for (int a = 0; a < 4; ++a) {
    const int R = a * HID + u0 + l;                    // gate*512 + unit
    const float2* p = (const float2*)(W_hh + (size_t)R * HID + 64 * cs);
#pragma unroll
    for (int k = 0; k < 32; ++k) {
      float2 q = p[k];
      w[a][k] = pack_h2(q.x, q.y);
    }
  }
  // ---- one-time: x0 column, y partials, gacc, arrive ----
  for (int i = tid; i < T_STEPS; i += BLK_THREADS) {
    x0_lds[i] = x0[i * BATCH + b];
    ylds[i] = 0.f;
  }
  if (tid < 256) { gacc[0][tid] = 0.f; gacc[1][tid] = 0.f; }
  if (tid < 2) arrive[tid] = 0;

  // ---- activation-lane constants (lanes 0..63 of wave 0) ----
  float c_state = 0.f;
  float wih_[4] = {0.f, 0.f, 0.f, 0.f}, bs_[4] = {0.f, 0.f, 0.f, 0.f};
  float wlin_u = 0.f, blin = 0.f;
  if (tid < 64) {
#pragma unroll
    for (int j = 0; j < 4; ++j) {
      int R = j * HID + u0 + tid;
      wih_[j] = W_ih[R];
      bs_[j] = b_ih[R] + b_hh[R];
    }
    wlin_u = W_lin[u0 + tid];
    blin = b_lin[0];
  }

  // ---- wave-uniform SGPR addresses (tagged-line record layout) ----
  uint32_t* hb = h_ex + (size_t)b * (GROUPS * 64);
  const uint64_t dpu[2] = { uni64(hb + 64 * cs),
                            uni64(hb + SLOT_DW + 64 * cs) };
  uint32_t* pub01[2] = { hb + 64 * g, hb + SLOT_DW + 64 * g };

  __syncthreads();

  int dead = 0;
  for (int t = 0; t < T_STEPS; ++t) {
    const int sl = t & 1, ns = sl ^ 1;

    // ---- fused poll+fetch: HOT spin (no sleep quantum on the detect) ----
    u32x8 D0, D1, D2, D3;
    uint32_t tg0, tg1, tg2, tg3;
    {
      const uint32_t want = (uint32_t)t;
      int guard = 0;
      for (;;) {
        kinv();
        sload_rec(dpu[sl], &D0, &D1, &D2, &D3, &tg0, &tg1, &tg2, &tg3);
        if ((tg0 == want) & (tg1 == want) &
            (tg2 == want) & (tg3 == want)) break;
        if (dead || ++guard > (1 << 14)) { dead = 1; break; }  // anti-hang
      }
    }

    // ---- matvec: 4 gate-rows x 64 cols per lane; 8 independent chains ----
    __builtin_amdgcn_s_setprio(1);
    float ae0 = 0.f, ao0 = 0.f, ae1 = 0.f, ao1 = 0.f;
    float ae2 = 0.f, ao2 = 0.f, ae3 = 0.f, ao3 = 0.f;
#pragma unroll
    for (int k = 0; k < 8; k += 2) {
      ae0 = fdot2(w[0][k], D0[k], ae0);      ao0 = fdot2(w[0][k + 1], D0[k + 1], ao0);
      ae1 = fdot2(w[1][k], D0[k], ae1);      ao1 = fdot2(w[1][k + 1], D0[k + 1], ao1);
      ae2 = fdot2(w[2][k], D0[k], ae2);      ao2 = fdot2(w[2][k + 1], D0[k + 1], ao2);
      ae3 = fdot2(w[3][k], D0[k], ae3);      ao3 = fdot2(w[3][k + 1], D0[k + 1], ao3);
      ae0 = fdot2(w[0][8 + k], D1[k], ae0);  ao0 = fdot2(w[0][9 + k], D1[k + 1], ao0);
      ae1 = fdot2(w[1][8 + k], D1[k], ae1);  ao1 = fdot2(w[1][9 + k], D1[k + 1], ao1);
      ae2 = fdot2(w[2][8 + k], D1[k], ae2);  ao2 = fdot2(w[2][9 + k], D1[k + 1], ao2);
      ae3 = fdot2(w[3][8 + k], D1[k], ae3);  ao3 = fdot2(w[3][9 + k], D1[k + 1], ao3);
      ae0 = fdot2(w[0][16 + k], D2[k], ae0); ao0 = fdot2(w[0][17 + k], D2[k + 1], ao0);
      ae1 = fdot2(w[1][16 + k], D2[k], ae1); ao1 = fdot2(w[1][17 + k], D2[k + 1], ao1);
      ae2 = fdot2(w[2][16 + k], D2[k], ae2); ao2 = fdot2(w[2][17 + k], D2[k + 1], ao2);
      ae3 = fdot2(w[3][16 + k], D2[k], ae3); ao3 = fdot2(w[3][17 + k], D2[k + 1], ao3);
      ae0 = fdot2(w[0][24 + k], D3[k], ae0); ao0 = fdot2(w[0][25 + k], D3[k + 1], ao0);
      ae1 = fdot2(w[1][24 + k], D3[k], ae1); ao1 = fdot2(w[1][25 + k], D3[k + 1], ao1);
      ae2 = fdot2(w[2][24 + k], D3[k], ae2); ao2 = fdot2(w[2][25 + k], D3[k + 1], ao2);
      ae3 = fdot2(w[3][24 + k], D3[k], ae3); ao3 = fdot2(w[3][25 + k], D3[k + 1], ao3);
    }
    atomicAdd(&gacc[sl][l],       ae0 + ao0);   // conflict-free across lanes
    atomicAdd(&gacc[sl][64 + l],  ae1 + ao1);
    atomicAdd(&gacc[sl][128 + l], ae2 + ao2);
    atomicAdd(&gacc[sl][192 + l], ae3 + ao3);
    asm volatile("" ::: "memory");       // adds ordered before the inc
    if (l == 0) atomicAdd(&arrive[sl], 1);
    __builtin_amdgcn_s_setprio(0);
    // waves 1-7 fall through to poll t+1 NOW (overlap wave 0's tail)

    // ---- activation + publish (wave 0 only; no block barrier) ----
    if (tid < 64) {
      {
        int guard = 0;
        while (((volatile int*)arrive)[sl] < 8) {   // hot spin, LDS only
          if (++guard > (1 << 20)) break;           // anti-hang
        }
      }
      asm volatile("" ::: "memory");
      __builtin_amdgcn_s_setprio(1);
      arrive[sl] = 0;                    // reset for t+2 (tag chain gates)

      const float xv = x0_lds[t];
      float gi = gacc[sl][tid]       + xv * wih_[0] + bs_[0];
      float gf = gacc[sl][tid + 64]  + xv * wih_[1] + bs_[1];
      float gg = gacc[sl][tid + 128] + xv * wih_[2] + bs_[2];
      float go = gacc[sl][tid + 192] + xv * wih_[3] + bs_[3];
      float si = sigf(gi), sf = sigf(gf), tg_ = tanh_fast(gg), so = sigf(go);
      c_state = sf * c_state + si * tg_;
      float h = so * tanh_fast(c_state);

      // publish: 36-lane predicated store of 4 self-certifying lines
      float hn = __shfl_down(h, 1, 64);
      uint32_t val = 0;
      int doff = 0;
      bool act = false;
      if ((tid & 1) == 0) {
        int j = tid >> 1;
        val = pack_h2(h, hn);
        doff = ((j >> 3) << 4) + (j & 7);
        act = true;
      } else if (tid < 8) {
        int L = (tid - 1) >> 1;
        val = (uint32_t)(t + 1);
        doff = (L << 4) + 8;
        act = true;
      }
      if (act) pub01[ns][doff] = val;

      // recycle gacc[sl] for t+2
      gacc[sl][tid] = 0.f;
      gacc[sl][tid + 64] = 0.f;
      gacc[sl][tid + 128] = 0.f;
      gacc[sl][tid + 192] = 0.f;

      // y partial (off critical path)
      float p = wlin_u * h;
#pragma unroll
      for (int m = 32; m >= 1; m >>= 1) p += __shfl_xor(p, m, 64);
      if (tid == 0) ylds[t] = p;
      __builtin_amdgcn_s_setprio(0);
    }
  }

  // ---- drain: block partials -> global y (g==0 adds bias + residual) ----
  __syncthreads();
  for (int i = tid; i < T_STEPS; i += BLK_THREADS) {
    float val = ylds[i];
    if (g == 0) val += blin + x0_lds[i];
    unsafeAtomicAdd(&y[i * BATCH + b], val);
  }
}

extern "C" void kernel_launch(void* const* d_in, const int* in_sizes, int n_in,
                              void* d_out, int out_size, void* d_ws, size_t ws_size,
                              hipStream_t stream) {
  const float* x0    = (const float*)d_in[0];
  const float* W_ih  = (const float*)d_in[1];
  const float* W_hh  = (const float*)d_in[2];
  const float* b_ih  = (const float*)d_in[3];
  const float* b_hh  = (const float*)d_in[4];
  const float* W_lin = (const float*)d_in[5];
  const float* b_lin = (const float*)d_in[6];
  float* y = (float*)d_out;

  uint32_t* h_ex = (uint32_t*)d_ws;                    // 2 x 64 KB slots
  int* claim     = (int*)(h_ex + 2 * SLOT_DW);         // 512 B
  const size_t init_bytes = (size_t)2 * SLOT_DW * sizeof(uint32_t)
                            + 8 * 16 * sizeof(int);

  // memset 0: slot-0 tags = 0 with h = 0 (== "h_0 available"), claim = 0
  (void)hipMemsetAsync(d_ws, 0, init_bytes, stream);
  (void)hipMemsetAsync(d_out, 0, (size_t)out_size * sizeof(float), stream);

  hipLaunchKernelGGL(lstm_w8, dim3(NBLOCKS), dim3(BLK_THREADS), 0, stream,
                     x0, W_ih, W_hh, b_ih, b_hh, W_lin, b_lin, y, h_ex, claim);
}